// Round 9
// baseline (177.578 us; speedup 1.0000x reference)
//
#include <hip/hip_runtime.h>

#define NQ 256
#define MK 1024
#define DD 512
#define CSC 2.8853900817779268f   // 2*log2(e): tanh(x) = 1 - 2/(exp2(CSC*x)+1)
#define L2E 1.4426950408889634f

typedef __attribute__((ext_vector_type(8))) short short8;
typedef __attribute__((ext_vector_type(4))) float floatx4;

// ---------------------------------------------------------------------------
// K0: split f32 -> bf16 hi/lo pairs for q,k,v,WQ,WK,WV. 1920 blocks x 256.
// ---------------------------------------------------------------------------
__device__ inline void bsplit(float x, unsigned short& h, unsigned short& l)
{
    unsigned u = __float_as_uint(x);
    unsigned hr = (u + 0x7FFFu + ((u >> 16) & 1u)) >> 16;   // RN bf16
    h = (unsigned short)hr;
    float hf = __uint_as_float(hr << 16);
    unsigned ul = __float_as_uint(x - hf);
    l = (unsigned short)((ul + 0x7FFFu + ((ul >> 16) & 1u)) >> 16);
}

__global__ __launch_bounds__(256) void convert_split(
    const float* __restrict__ q, const float* __restrict__ k, const float* __restrict__ v,
    const float* __restrict__ WQ, const float* __restrict__ WK, const float* __restrict__ WV,
    unsigned short* __restrict__ qhi, unsigned short* __restrict__ qlo,
    unsigned short* __restrict__ khi, unsigned short* __restrict__ klo,
    unsigned short* __restrict__ vhi, unsigned short* __restrict__ vlo,
    unsigned short* __restrict__ wqhi, unsigned short* __restrict__ wqlo,
    unsigned short* __restrict__ wkhi, unsigned short* __restrict__ wklo,
    unsigned short* __restrict__ wvhi, unsigned short* __restrict__ wvlo)
{
    const int i = blockIdx.x * 256 + threadIdx.x;   // float4 index
    const float* src; unsigned short *dh, *dl; int li;
    if (i < 32768)       { src = q;  dh = qhi;  dl = qlo;  li = i; }
    else if (i < 163840) { src = k;  dh = khi;  dl = klo;  li = i - 32768; }
    else if (i < 294912) { src = v;  dh = vhi;  dl = vlo;  li = i - 163840; }
    else if (i < 360448) { src = WQ; dh = wqhi; dl = wqlo; li = i - 294912; }
    else if (i < 425984) { src = WK; dh = wkhi; dl = wklo; li = i - 360448; }
    else                 { src = WV; dh = wvhi; dl = wvlo; li = i - 425984; }

    float4 x = *(const float4*)&src[li * 4];
    ushort4 h, l;
    bsplit(x.x, h.x, l.x); bsplit(x.y, h.y, l.y);
    bsplit(x.z, h.z, l.z); bsplit(x.w, h.w, l.w);
    *(ushort4*)&dh[li * 4] = h;
    *(ushort4*)&dl[li * 4] = l;
}

// ---------------------------------------------------------------------------
// K1: projections via split-bf16 MFMA:  out = Xhi@Whi^T + Xhi@Wlo^T + Xlo@Whi^T
// 288 blocks, 4 waves, 64x64 tile (wave = 16-row strip, 4 n-tiles).
//   mode 0: qs  = CSC*(q@WQ.T+bQ)            [256x512]
//   mode 1: kts = CSC*(k@WK.T+bK) TRANSPOSED [512x1024] (kts[d][m])
//   mode 2: vp  = v@WV.T+bV                  [1024x512]
// ---------------------------------------------------------------------------
__global__ __launch_bounds__(256) void proj_mfma(
    const unsigned short* __restrict__ qhi, const unsigned short* __restrict__ qlo,
    const unsigned short* __restrict__ khi, const unsigned short* __restrict__ klo,
    const unsigned short* __restrict__ vhi, const unsigned short* __restrict__ vlo,
    const unsigned short* __restrict__ wqhi, const unsigned short* __restrict__ wqlo,
    const unsigned short* __restrict__ wkhi, const unsigned short* __restrict__ wklo,
    const unsigned short* __restrict__ wvhi, const unsigned short* __restrict__ wvlo,
    const float* __restrict__ bQ, const float* __restrict__ bK, const float* __restrict__ bV,
    float* __restrict__ qs, float* __restrict__ kts, float* __restrict__ vp)
{
    int t = blockIdx.x;
    const unsigned short *Xh, *Xl, *Wh, *Wl; const float* b; int mode;
    if (t < 32)       { mode = 0; Xh = qhi; Xl = qlo; Wh = wqhi; Wl = wqlo; b = bQ; }
    else if (t < 160) { mode = 1; t -= 32;  Xh = khi; Xl = klo; Wh = wkhi; Wl = wklo; b = bK; }
    else              { mode = 2; t -= 160; Xh = vhi; Xl = vlo; Wh = wvhi; Wl = wvlo; b = bV; }
    const int i0 = (t >> 3) * 64;
    const int j0 = (t & 7) * 64;

    const int l  = threadIdx.x & 63;
    const int w  = threadIdx.x >> 6;
    const int lr = l & 15;             // A-row / B-col / D-col within tile
    const int lk = (l >> 4) * 8;       // k-slice offset
    const int rbase = (l >> 4) * 4;    // D-row base

    const int arow = (i0 + w * 16 + lr) * DD;

    floatx4 acc[4] = {{0,0,0,0},{0,0,0,0},{0,0,0,0},{0,0,0,0}};

    for (int kk = 0; kk < DD; kk += 32) {
        short8 ah = *(const short8*)&Xh[arow + kk + lk];
        short8 al = *(const short8*)&Xl[arow + kk + lk];
#pragma unroll
        for (int nt = 0; nt < 4; ++nt) {
            const int brow = (j0 + nt * 16 + lr) * DD;
            short8 bh = *(const short8*)&Wh[brow + kk + lk];
            short8 bl = *(const short8*)&Wl[brow + kk + lk];
            acc[nt] = __builtin_amdgcn_mfma_f32_16x16x32_bf16(ah, bh, acc[nt], 0, 0, 0);
            acc[nt] = __builtin_amdgcn_mfma_f32_16x16x32_bf16(ah, bl, acc[nt], 0, 0, 0);
            acc[nt] = __builtin_amdgcn_mfma_f32_16x16x32_bf16(al, bh, acc[nt], 0, 0, 0);
        }
    }

    if (mode == 1) {
#pragma unroll
        for (int nt = 0; nt < 4; ++nt) {
            const float bb = b[j0 + nt * 16 + lr];
            float4 o;
            o.x = (acc[nt][0] + bb) * CSC;
            o.y = (acc[nt][1] + bb) * CSC;
            o.z = (acc[nt][2] + bb) * CSC;
            o.w = (acc[nt][3] + bb) * CSC;
            *(float4*)&kts[(j0 + nt * 16 + lr) * MK + i0 + w * 16 + rbase] = o;
        }
    } else {
        float* dst = (mode == 0) ? qs : vp;
        const float sc = (mode == 0) ? CSC : 1.0f;
#pragma unroll
        for (int nt = 0; nt < 4; ++nt) {
            const float bb = b[j0 + nt * 16 + lr];
#pragma unroll
            for (int j = 0; j < 4; ++j)
                dst[(i0 + w * 16 + rbase + j) * DD + j0 + nt * 16 + lr]
                    = (acc[nt][j] + bb) * sc;
        }
    }
}

// ---------------------------------------------------------------------------
// K2: fused scores + softmax. One block per query row; thread t = key m.
// q-row & Ww staged in LDS once (broadcast reads); kts streamed coalesced.
// Softmax is shift-invariant -> the (sum(Ww)+bw) constant cancels and is
// dropped; masked entries are absolute -1e6 in both formulations.
//   s'[m] = -2 * sum_d Ww[d]*rcp(exp2(qs[n,d]+kts[d,m])+1)   (or -1e6 masked)
//   S[n][m] = softmax_m(s')  (final weights; no separate softmax pass)
// ---------------------------------------------------------------------------
__global__ __launch_bounds__(1024) void score_sm(
    const float* __restrict__ qs, const float* __restrict__ kts,
    const float* __restrict__ Ww, const int* __restrict__ mask,
    float* __restrict__ S)
{
    const int n = blockIdx.x;
    const int t = threadIdx.x;            // key index m
    const int lane = t & 63, wave = t >> 6;

    __shared__ float qsm[DD];
    __shared__ float wwm[DD];
    __shared__ float red[16];

    if (t < DD) { qsm[t] = qs[n * DD + t]; wwm[t] = Ww[t]; }
    __syncthreads();

    float acc = 0.f;
    for (int d = 0; d < DD; d += 8) {
        float kv[8];
#pragma unroll
        for (int j = 0; j < 8; ++j) kv[j] = kts[(d + j) * MK + t];
#pragma unroll
        for (int j = 0; j < 8; ++j) {
            float x = qsm[d + j] + kv[j];
            float e = __builtin_amdgcn_exp2f(x);
            acc = fmaf(wwm[d + j], __builtin_amdgcn_rcpf(e + 1.0f), acc);
        }
    }

    float s = -2.0f * acc;
    s = (mask[n * MK + t] == 1) ? s : -1e6f;

    // block max
    float mx = s;
    for (int o = 32; o > 0; o >>= 1) mx = fmaxf(mx, __shfl_xor(mx, o, 64));
    if (lane == 0) red[wave] = mx;
    __syncthreads();
    if (wave == 0) {
        float r = red[lane & 15];
        for (int o = 8; o > 0; o >>= 1) r = fmaxf(r, __shfl_xor(r, o, 64));
        if (lane == 0) red[0] = r;
    }
    __syncthreads();
    mx = red[0];
    __syncthreads();

    // block sum of exp
    float e = __builtin_amdgcn_exp2f((s - mx) * L2E);
    float sum = e;
    for (int o = 32; o > 0; o >>= 1) sum += __shfl_xor(sum, o, 64);
    if (lane == 0) red[wave] = sum;
    __syncthreads();
    if (wave == 0) {
        float r = red[lane & 15];
        for (int o = 8; o > 0; o >>= 1) r += __shfl_xor(r, o, 64);
        if (lane == 0) red[0] = r;
    }
    __syncthreads();
    sum = red[0];

    S[n * MK + t] = e * __builtin_amdgcn_rcpf(sum);
}

// ---------------------------------------------------------------------------
// K4: context[n][d] = sum_m w[n][m]*vp[m][d]. 8 queries x 256-key chunk per
// block; weights in LDS [m][n] read as broadcast float4; atomics combine.
// ---------------------------------------------------------------------------
#define CNG 8
#define CMC 256

__global__ __launch_bounds__(512) void context_v2(const float* __restrict__ S,
                                                  const float* __restrict__ vp,
                                                  float* __restrict__ out)
{
    __shared__ float ws[CMC][12];   // [m][n], padded to 48B for aligned float4
    const int t = threadIdx.x;
    const int n0 = blockIdx.x * CNG;
    const int m0 = blockIdx.y * CMC;

#pragma unroll
    for (int p = 0; p < 4; ++p) {
        int e = t + p * 512;
        int m = e & 255, n = e >> 8;
        ws[m][n] = S[(n0 + n) * MK + m0 + m];
    }
    __syncthreads();

    float acc[CNG] = {};
    for (int m = 0; m < CMC; ++m) {
        float vv = vp[(m0 + m) * DD + t];
        float4 w0 = *(const float4*)&ws[m][0];
        float4 w4 = *(const float4*)&ws[m][4];
        acc[0] = fmaf(w0.x, vv, acc[0]);
        acc[1] = fmaf(w0.y, vv, acc[1]);
        acc[2] = fmaf(w0.z, vv, acc[2]);
        acc[3] = fmaf(w0.w, vv, acc[3]);
        acc[4] = fmaf(w4.x, vv, acc[4]);
        acc[5] = fmaf(w4.y, vv, acc[5]);
        acc[6] = fmaf(w4.z, vv, acc[6]);
        acc[7] = fmaf(w4.w, vv, acc[7]);
    }
#pragma unroll
    for (int n = 0; n < CNG; ++n) atomicAdd(&out[(n0 + n) * DD + t], acc[n]);
}

// ---------------------------------------------------------------------------
extern "C" void kernel_launch(void* const* d_in, const int* in_sizes, int n_in,
                              void* d_out, int out_size, void* d_ws, size_t ws_size,
                              hipStream_t stream)
{
    const float* q    = (const float*)d_in[0];
    const float* k    = (const float*)d_in[1];
    const float* v    = (const float*)d_in[2];
    const int*   mask = (const int*)  d_in[3];
    const float* WQ   = (const float*)d_in[4];
    const float* bQ   = (const float*)d_in[5];
    const float* WK   = (const float*)d_in[6];
    const float* bK   = (const float*)d_in[7];
    const float* WV   = (const float*)d_in[8];
    const float* bV   = (const float*)d_in[9];
    const float* Ww   = (const float*)d_in[10];
    const float* bw   = (const float*)d_in[11];
    (void)bw;  // cancels in softmax (shift invariance)
    float* out = (float*)d_out;

    // f32 workspace
    float* qs  = (float*)d_ws;           // 131072
    float* kts = qs + NQ * DD;           // 524288 (transposed, scaled)
    float* vp  = kts + DD * MK;          // 524288
    float* S   = vp + MK * DD;           // 262144 (final softmax weights)
    // bf16 hi/lo workspace
    unsigned short* p16  = (unsigned short*)(S + NQ * MK);
    unsigned short* qhi  = p16;              p16 += NQ * DD;
    unsigned short* qlo  = p16;              p16 += NQ * DD;
    unsigned short* khi  = p16;              p16 += MK * DD;
    unsigned short* klo  = p16;              p16 += MK * DD;
    unsigned short* vhi  = p16;              p16 += MK * DD;
    unsigned short* vlo  = p16;              p16 += MK * DD;
    unsigned short* wqhi = p16;              p16 += DD * DD;
    unsigned short* wqlo = p16;              p16 += DD * DD;
    unsigned short* wkhi = p16;              p16 += DD * DD;
    unsigned short* wklo = p16;              p16 += DD * DD;
    unsigned short* wvhi = p16;              p16 += DD * DD;
    unsigned short* wvlo = p16;

    hipMemsetAsync(d_out, 0, (size_t)NQ * DD * sizeof(float), stream);

    convert_split<<<1920, 256, 0, stream>>>(q, k, v, WQ, WK, WV,
        qhi, qlo, khi, klo, vhi, vlo, wqhi, wqlo, wkhi, wklo, wvhi, wvlo);

    proj_mfma<<<288, 256, 0, stream>>>(qhi, qlo, khi, klo, vhi, vlo,
        wqhi, wqlo, wkhi, wklo, wvhi, wvlo, bQ, bK, bV, qs, kts, vp);

    score_sm<<<NQ, 1024, 0, stream>>>(qs, kts, Ww, mask, S);

    context_v2<<<dim3(NQ / CNG, MK / CMC), dim3(512), 0, stream>>>(S, vp, out);
}

// Round 10
// 158.385 us; speedup vs baseline: 1.1212x; 1.1212x over previous
//
#include <hip/hip_runtime.h>

#define NQ 256
#define MK 1024
#define DD 512
#define CSC 2.8853900817779268f   // 2*log2(e): tanh(x) = 1 - 2/(exp2(CSC*x)+1)
#define L2E 1.4426950408889634f

typedef __attribute__((ext_vector_type(8))) short short8;
typedef __attribute__((ext_vector_type(4))) float floatx4;

// Swizzled MFMA-fragment layout for row-major [rows][512] bf16 arrays:
// element (i,d) -> ((i/16)*16 + d/32)*512 + ((d/8)&3)*128 + (i&15)*8 + (d&7).
// A wave's 16x32 fragment tile = one contiguous 1KB block (lane l at l*8).
__device__ inline int swz(int i, int d)
{
    return (((i >> 4) * 16 + (d >> 5)) << 9) | (((d >> 3) & 3) << 7)
         | ((i & 15) << 3) | (d & 7);
}

// ---------------------------------------------------------------------------
// K0: split f32 -> bf16 hi/lo pairs (swizzled layout). 1920 blocks x 256.
// ---------------------------------------------------------------------------
__device__ inline void bsplit(float x, unsigned short& h, unsigned short& l)
{
    unsigned u = __float_as_uint(x);
    unsigned hr = (u + 0x7FFFu + ((u >> 16) & 1u)) >> 16;   // RN bf16
    h = (unsigned short)hr;
    float hf = __uint_as_float(hr << 16);
    unsigned ul = __float_as_uint(x - hf);
    l = (unsigned short)((ul + 0x7FFFu + ((ul >> 16) & 1u)) >> 16);
}

__global__ __launch_bounds__(256) void convert_split(
    const float* __restrict__ q, const float* __restrict__ k, const float* __restrict__ v,
    const float* __restrict__ WQ, const float* __restrict__ WK, const float* __restrict__ WV,
    unsigned short* __restrict__ qhi, unsigned short* __restrict__ qlo,
    unsigned short* __restrict__ khi, unsigned short* __restrict__ klo,
    unsigned short* __restrict__ vhi, unsigned short* __restrict__ vlo,
    unsigned short* __restrict__ wqhi, unsigned short* __restrict__ wqlo,
    unsigned short* __restrict__ wkhi, unsigned short* __restrict__ wklo,
    unsigned short* __restrict__ wvhi, unsigned short* __restrict__ wvlo)
{
    const int i4 = blockIdx.x * 256 + threadIdx.x;   // float4 index
    const float* src; unsigned short *dh, *dl; int li;
    if (i4 < 32768)       { src = q;  dh = qhi;  dl = qlo;  li = i4; }
    else if (i4 < 163840) { src = k;  dh = khi;  dl = klo;  li = i4 - 32768; }
    else if (i4 < 294912) { src = v;  dh = vhi;  dl = vlo;  li = i4 - 163840; }
    else if (i4 < 360448) { src = WQ; dh = wqhi; dl = wqlo; li = i4 - 294912; }
    else if (i4 < 425984) { src = WK; dh = wkhi; dl = wklo; li = i4 - 360448; }
    else                  { src = WV; dh = wvhi; dl = wvlo; li = i4 - 425984; }

    float4 x = *(const float4*)&src[li * 4];
    ushort4 h, l;
    bsplit(x.x, h.x, l.x); bsplit(x.y, h.y, l.y);
    bsplit(x.z, h.z, l.z); bsplit(x.w, h.w, l.w);

    const int e = li * 4;                 // element index; d%4==0
    const int o = swz(e >> 9, e & 511);   // 8B-aligned (d&7 in {0,4})
    *(ushort4*)&dh[o] = h;
    *(ushort4*)&dl[o] = l;
}

// ---------------------------------------------------------------------------
// K1: projections via split-bf16 MFMA, swizzled-coalesced fragment loads.
// 288 blocks, 4 waves, 64x64 tile (wave = 16-row strip, 4 n-tiles).
//   mode 0: qs  = CSC*(q@WQ.T+bQ)          [256x512] row-major
//   mode 1: kt8 = CSC*(k@WK.T+bK) TILED    kt8[(d>>3)*MK+m)*8+(d&7)]
//   mode 2: vp  = v@WV.T+bV                [1024x512] row-major
// ---------------------------------------------------------------------------
__global__ __launch_bounds__(256) void proj_mfma(
    const unsigned short* __restrict__ qhi, const unsigned short* __restrict__ qlo,
    const unsigned short* __restrict__ khi, const unsigned short* __restrict__ klo,
    const unsigned short* __restrict__ vhi, const unsigned short* __restrict__ vlo,
    const unsigned short* __restrict__ wqhi, const unsigned short* __restrict__ wqlo,
    const unsigned short* __restrict__ wkhi, const unsigned short* __restrict__ wklo,
    const unsigned short* __restrict__ wvhi, const unsigned short* __restrict__ wvlo,
    const float* __restrict__ bQ, const float* __restrict__ bK, const float* __restrict__ bV,
    float* __restrict__ qs, float* __restrict__ kts, float* __restrict__ vp)
{
    int t = blockIdx.x;
    const unsigned short *Xh, *Xl, *Wh, *Wl; const float* b; int mode;
    if (t < 32)       { mode = 0; Xh = qhi; Xl = qlo; Wh = wqhi; Wl = wqlo; b = bQ; }
    else if (t < 160) { mode = 1; t -= 32;  Xh = khi; Xl = klo; Wh = wkhi; Wl = wklo; b = bK; }
    else              { mode = 2; t -= 160; Xh = vhi; Xl = vlo; Wh = wvhi; Wl = wvlo; b = bV; }
    const int i0 = (t >> 3) * 64;
    const int j0 = (t & 7) * 64;

    const int l  = threadIdx.x & 63;
    const int w  = threadIdx.x >> 6;
    const int lr = l & 15;             // A-row / B-col / D-col within tile
    const int rbase = (l >> 4) * 4;    // D-row base

    const unsigned short* Ah = Xh + ((i0 >> 4) + w) * 8192 + l * 8;
    const unsigned short* Al = Xl + ((i0 >> 4) + w) * 8192 + l * 8;
    const unsigned short* Bh = Wh + (j0 >> 4) * 8192 + l * 8;
    const unsigned short* Bl = Wl + (j0 >> 4) * 8192 + l * 8;

    floatx4 acc[4] = {{0,0,0,0},{0,0,0,0},{0,0,0,0},{0,0,0,0}};

#pragma unroll
    for (int kc = 0; kc < 16; ++kc) {
        short8 ah = *(const short8*)(Ah + kc * 512);
        short8 al = *(const short8*)(Al + kc * 512);
#pragma unroll
        for (int nt = 0; nt < 4; ++nt) {
            short8 bh = *(const short8*)(Bh + nt * 8192 + kc * 512);
            short8 bl = *(const short8*)(Bl + nt * 8192 + kc * 512);
            acc[nt] = __builtin_amdgcn_mfma_f32_16x16x32_bf16(ah, bh, acc[nt], 0, 0, 0);
            acc[nt] = __builtin_amdgcn_mfma_f32_16x16x32_bf16(ah, bl, acc[nt], 0, 0, 0);
            acc[nt] = __builtin_amdgcn_mfma_f32_16x16x32_bf16(al, bh, acc[nt], 0, 0, 0);
        }
    }

    if (mode == 1) {
#pragma unroll
        for (int nt = 0; nt < 4; ++nt) {
            const int d = j0 + nt * 16 + lr;
            const float bb = b[d];
            float* base = &kts[(((d >> 3) * MK) + i0 + w * 16 + rbase) * 8 + (d & 7)];
#pragma unroll
            for (int j = 0; j < 4; ++j)
                base[j * 8] = (acc[nt][j] + bb) * CSC;
        }
    } else {
        float* dst = (mode == 0) ? qs : vp;
        const float sc = (mode == 0) ? CSC : 1.0f;
#pragma unroll
        for (int nt = 0; nt < 4; ++nt) {
            const float bb = b[j0 + nt * 16 + lr];
#pragma unroll
            for (int j = 0; j < 4; ++j)
                dst[(i0 + w * 16 + rbase + j) * DD + j0 + nt * 16 + lr]
                    = (acc[nt][j] + bb) * sc;
        }
    }
}

// ---------------------------------------------------------------------------
// K2: fused scores + softmax. One block per query row; thread t = key m.
// kt8 tiled reads: 8 contiguous floats/thread/chunk (2 coalesced float4).
// qs/Ww packed float2 in LDS -> one ds_read_b64 broadcast per element.
//   s'[m] = -2 * sum_d Ww[d]*rcp(exp2(qs[n,d]+kt[d,m])+1)  (or -1e6 masked)
//   S[n][m] = softmax_m(s')   ((sum(Ww)+bw) shift cancels in softmax)
// ---------------------------------------------------------------------------
__global__ __launch_bounds__(1024) void score_sm(
    const float* __restrict__ qs, const float* __restrict__ kts,
    const float* __restrict__ Ww, const int* __restrict__ mask,
    float* __restrict__ S)
{
    const int n = blockIdx.x;
    const int t = threadIdx.x;            // key index m
    const int lane = t & 63, wave = t >> 6;

    __shared__ float qw[DD * 2];          // packed (qs, Ww) pairs
    __shared__ float red[16];

    if (t < DD) { qw[t * 2] = qs[n * DD + t]; qw[t * 2 + 1] = Ww[t]; }
    __syncthreads();

    const float* kp = kts + t * 8;
    float acc = 0.f;
    for (int c = 0; c < 64; ++c) {
        float4 k0 = *(const float4*)(kp + c * (MK * 8));
        float4 k1 = *(const float4*)(kp + c * (MK * 8) + 4);
        float kv[8] = {k0.x, k0.y, k0.z, k0.w, k1.x, k1.y, k1.z, k1.w};
#pragma unroll
        for (int j = 0; j < 8; ++j) {
            float2 wq = *(const float2*)&qw[(c * 8 + j) * 2];
            float e = __builtin_amdgcn_exp2f(wq.x + kv[j]);
            acc = fmaf(wq.y, __builtin_amdgcn_rcpf(e + 1.0f), acc);
        }
    }

    float s = -2.0f * acc;
    s = (mask[n * MK + t] == 1) ? s : -1e6f;

    // block max
    float mx = s;
    for (int o = 32; o > 0; o >>= 1) mx = fmaxf(mx, __shfl_xor(mx, o, 64));
    if (lane == 0) red[wave] = mx;
    __syncthreads();
    if (wave == 0) {
        float r = red[lane & 15];
        for (int o = 8; o > 0; o >>= 1) r = fmaxf(r, __shfl_xor(r, o, 64));
        if (lane == 0) red[0] = r;
    }
    __syncthreads();
    mx = red[0];
    __syncthreads();

    // block sum of exp
    float e = __builtin_amdgcn_exp2f((s - mx) * L2E);
    float sum = e;
    for (int o = 32; o > 0; o >>= 1) sum += __shfl_xor(sum, o, 64);
    if (lane == 0) red[wave] = sum;
    __syncthreads();
    if (wave == 0) {
        float r = red[lane & 15];
        for (int o = 8; o > 0; o >>= 1) r += __shfl_xor(r, o, 64);
        if (lane == 0) red[0] = r;
    }
    __syncthreads();
    sum = red[0];

    S[n * MK + t] = e * __builtin_amdgcn_rcpf(sum);
}

// ---------------------------------------------------------------------------
// K4: context[n][d] = sum_m w[n][m]*vp[m][d]. 8 queries x 256-key chunk per
// block; weights in LDS [m][n] read as broadcast float4; atomics combine.
// ---------------------------------------------------------------------------
#define CNG 8
#define CMC 256

__global__ __launch_bounds__(512) void context_v2(const float* __restrict__ S,
                                                  const float* __restrict__ vp,
                                                  float* __restrict__ out)
{
    __shared__ float ws[CMC][12];   // [m][n], padded to 48B for aligned float4
    const int t = threadIdx.x;
    const int n0 = blockIdx.x * CNG;
    const int m0 = blockIdx.y * CMC;

#pragma unroll
    for (int p = 0; p < 4; ++p) {
        int e = t + p * 512;
        int m = e & 255, n = e >> 8;
        ws[m][n] = S[(n0 + n) * MK + m0 + m];
    }
    __syncthreads();

    float acc[CNG] = {};
    for (int m = 0; m < CMC; ++m) {
        float vv = vp[(m0 + m) * DD + t];
        float4 w0 = *(const float4*)&ws[m][0];
        float4 w4 = *(const float4*)&ws[m][4];
        acc[0] = fmaf(w0.x, vv, acc[0]);
        acc[1] = fmaf(w0.y, vv, acc[1]);
        acc[2] = fmaf(w0.z, vv, acc[2]);
        acc[3] = fmaf(w0.w, vv, acc[3]);
        acc[4] = fmaf(w4.x, vv, acc[4]);
        acc[5] = fmaf(w4.y, vv, acc[5]);
        acc[6] = fmaf(w4.z, vv, acc[6]);
        acc[7] = fmaf(w4.w, vv, acc[7]);
    }
#pragma unroll
    for (int n = 0; n < CNG; ++n) atomicAdd(&out[(n0 + n) * DD + t], acc[n]);
}

// ---------------------------------------------------------------------------
extern "C" void kernel_launch(void* const* d_in, const int* in_sizes, int n_in,
                              void* d_out, int out_size, void* d_ws, size_t ws_size,
                              hipStream_t stream)
{
    const float* q    = (const float*)d_in[0];
    const float* k    = (const float*)d_in[1];
    const float* v    = (const float*)d_in[2];
    const int*   mask = (const int*)  d_in[3];
    const float* WQ   = (const float*)d_in[4];
    const float* bQ   = (const float*)d_in[5];
    const float* WK   = (const float*)d_in[6];
    const float* bK   = (const float*)d_in[7];
    const float* WV   = (const float*)d_in[8];
    const float* bV   = (const float*)d_in[9];
    const float* Ww   = (const float*)d_in[10];
    const float* bw   = (const float*)d_in[11];
    (void)bw;  // cancels in softmax (shift invariance)
    float* out = (float*)d_out;

    // f32 workspace
    float* qs  = (float*)d_ws;           // 131072
    float* kts = qs + NQ * DD;           // 524288 (tiled kt8 layout)
    float* vp  = kts + DD * MK;          // 524288
    float* S   = vp + MK * DD;           // 262144 (final softmax weights)
    // bf16 hi/lo workspace (swizzled fragment layout)
    unsigned short* p16  = (unsigned short*)(S + NQ * MK);
    unsigned short* qhi  = p16;              p16 += NQ * DD;
    unsigned short* qlo  = p16;              p16 += NQ * DD;
    unsigned short* khi  = p16;              p16 += MK * DD;
    unsigned short* klo  = p16;              p16 += MK * DD;
    unsigned short* vhi  = p16;              p16 += MK * DD;
    unsigned short* vlo  = p16;              p16 += MK * DD;
    unsigned short* wqhi = p16;              p16 += DD * DD;
    unsigned short* wqlo = p16;              p16 += DD * DD;
    unsigned short* wkhi = p16;              p16 += DD * DD;
    unsigned short* wklo = p16;              p16 += DD * DD;
    unsigned short* wvhi = p16;              p16 += DD * DD;
    unsigned short* wvlo = p16;

    hipMemsetAsync(d_out, 0, (size_t)NQ * DD * sizeof(float), stream);

    convert_split<<<1920, 256, 0, stream>>>(q, k, v, WQ, WK, WV,
        qhi, qlo, khi, klo, vhi, vlo, wqhi, wqlo, wkhi, wklo, wvhi, wvlo);

    proj_mfma<<<288, 256, 0, stream>>>(qhi, qlo, khi, klo, vhi, vlo,
        wqhi, wqlo, wkhi, wklo, wvhi, wvlo, bQ, bK, bV, qs, kts, vp);

    score_sm<<<NQ, 1024, 0, stream>>>(qs, kts, Ww, mask, S);

    context_v2<<<dim3(NQ / CNG, MK / CMC), dim3(512), 0, stream>>>(S, vp, out);
}

// Round 12
// 144.654 us; speedup vs baseline: 1.2276x; 1.0949x over previous
//
#include <hip/hip_runtime.h>

#define NQ 256
#define MK 1024
#define DD 512
#define CSC 2.8853900817779268f   // 2*log2(e): tanh(x) = 1 - 2/(exp2(CSC*x)+1)
#define L2E 1.4426950408889634f

typedef __attribute__((ext_vector_type(8))) short short8;
typedef __attribute__((ext_vector_type(4))) float floatx4;

// Swizzled MFMA-fragment layout for row-major [rows][512] bf16 arrays:
// element (i,d) -> ((i/16)*16 + d/32)*512 + ((d/8)&3)*128 + (i&15)*8 + (d&7).
// A wave's 16x32 fragment tile = one contiguous 1KB block (lane l at l*8).
__device__ inline int swz(int i, int d)
{
    return (((i >> 4) * 16 + (d >> 5)) << 9) | (((d >> 3) & 3) << 7)
         | ((i & 15) << 3) | (d & 7);
}

// ---------------------------------------------------------------------------
// K0: split f32 -> bf16 hi/lo pairs (swizzled layout). 1920 blocks x 256.
// ---------------------------------------------------------------------------
__device__ inline void bsplit(float x, unsigned short& h, unsigned short& l)
{
    unsigned u = __float_as_uint(x);
    unsigned hr = (u + 0x7FFFu + ((u >> 16) & 1u)) >> 16;   // RN bf16
    h = (unsigned short)hr;
    float hf = __uint_as_float(hr << 16);
    unsigned ul = __float_as_uint(x - hf);
    l = (unsigned short)((ul + 0x7FFFu + ((ul >> 16) & 1u)) >> 16);
}

__global__ __launch_bounds__(256) void convert_split(
    const float* __restrict__ q, const float* __restrict__ k, const float* __restrict__ v,
    const float* __restrict__ WQ, const float* __restrict__ WK, const float* __restrict__ WV,
    unsigned short* __restrict__ qhi, unsigned short* __restrict__ qlo,
    unsigned short* __restrict__ khi, unsigned short* __restrict__ klo,
    unsigned short* __restrict__ vhi, unsigned short* __restrict__ vlo,
    unsigned short* __restrict__ wqhi, unsigned short* __restrict__ wqlo,
    unsigned short* __restrict__ wkhi, unsigned short* __restrict__ wklo,
    unsigned short* __restrict__ wvhi, unsigned short* __restrict__ wvlo)
{
    const int i4 = blockIdx.x * 256 + threadIdx.x;   // float4 index
    const float* src; unsigned short *dh, *dl; int li;
    if (i4 < 32768)       { src = q;  dh = qhi;  dl = qlo;  li = i4; }
    else if (i4 < 163840) { src = k;  dh = khi;  dl = klo;  li = i4 - 32768; }
    else if (i4 < 294912) { src = v;  dh = vhi;  dl = vlo;  li = i4 - 163840; }
    else if (i4 < 360448) { src = WQ; dh = wqhi; dl = wqlo; li = i4 - 294912; }
    else if (i4 < 425984) { src = WK; dh = wkhi; dl = wklo; li = i4 - 360448; }
    else                  { src = WV; dh = wvhi; dl = wvlo; li = i4 - 425984; }

    float4 x = *(const float4*)&src[li * 4];
    ushort4 h, l;
    bsplit(x.x, h.x, l.x); bsplit(x.y, h.y, l.y);
    bsplit(x.z, h.z, l.z); bsplit(x.w, h.w, l.w);

    const int e = li * 4;                 // element index; d%4==0
    const int o = swz(e >> 9, e & 511);   // 8B-aligned (d&7 in {0,4})
    *(ushort4*)&dh[o] = h;
    *(ushort4*)&dl[o] = l;
}

// ---------------------------------------------------------------------------
// K1: projections via split-bf16 MFMA, swizzled-coalesced fragment loads.
// 288 blocks, 4 waves, 64x64 tile (wave = 16-row strip, 4 n-tiles).
//   mode 0: qe  = exp2(CSC*(q@WQ.T+bQ))          [256x512] row-major
//   mode 1: ke  = exp2(CSC*(k@WK.T+bK)) TILED    ke[((d>>3)*MK+m)*8+(d&7)]
//   mode 2: vp  = v@WV.T+bV                      [1024x512] row-major
// (score uses exp2(a+b) = exp2(a)*exp2(b); args bounded ~|15| -> no overflow)
// ---------------------------------------------------------------------------
__global__ __launch_bounds__(256) void proj_mfma(
    const unsigned short* __restrict__ qhi, const unsigned short* __restrict__ qlo,
    const unsigned short* __restrict__ khi, const unsigned short* __restrict__ klo,
    const unsigned short* __restrict__ vhi, const unsigned short* __restrict__ vlo,
    const unsigned short* __restrict__ wqhi, const unsigned short* __restrict__ wqlo,
    const unsigned short* __restrict__ wkhi, const unsigned short* __restrict__ wklo,
    const unsigned short* __restrict__ wvhi, const unsigned short* __restrict__ wvlo,
    const float* __restrict__ bQ, const float* __restrict__ bK, const float* __restrict__ bV,
    float* __restrict__ qe, float* __restrict__ ke, float* __restrict__ vp)
{
    int t = blockIdx.x;
    const unsigned short *Xh, *Xl, *Wh, *Wl; const float* b; int mode;
    if (t < 32)       { mode = 0; Xh = qhi; Xl = qlo; Wh = wqhi; Wl = wqlo; b = bQ; }
    else if (t < 160) { mode = 1; t -= 32;  Xh = khi; Xl = klo; Wh = wkhi; Wl = wklo; b = bK; }
    else              { mode = 2; t -= 160; Xh = vhi; Xl = vlo; Wh = wvhi; Wl = wvlo; b = bV; }
    const int i0 = (t >> 3) * 64;
    const int j0 = (t & 7) * 64;

    const int l  = threadIdx.x & 63;
    const int w  = threadIdx.x >> 6;
    const int lr = l & 15;             // A-row / B-col / D-col within tile
    const int rbase = (l >> 4) * 4;    // D-row base

    const unsigned short* Ah = Xh + ((i0 >> 4) + w) * 8192 + l * 8;
    const unsigned short* Al = Xl + ((i0 >> 4) + w) * 8192 + l * 8;
    const unsigned short* Bh = Wh + (j0 >> 4) * 8192 + l * 8;
    const unsigned short* Bl = Wl + (j0 >> 4) * 8192 + l * 8;

    floatx4 acc[4] = {{0,0,0,0},{0,0,0,0},{0,0,0,0},{0,0,0,0}};

#pragma unroll
    for (int kc = 0; kc < 16; ++kc) {
        short8 ah = *(const short8*)(Ah + kc * 512);
        short8 al = *(const short8*)(Al + kc * 512);
#pragma unroll
        for (int nt = 0; nt < 4; ++nt) {
            short8 bh = *(const short8*)(Bh + nt * 8192 + kc * 512);
            short8 bl = *(const short8*)(Bl + nt * 8192 + kc * 512);
            acc[nt] = __builtin_amdgcn_mfma_f32_16x16x32_bf16(ah, bh, acc[nt], 0, 0, 0);
            acc[nt] = __builtin_amdgcn_mfma_f32_16x16x32_bf16(ah, bl, acc[nt], 0, 0, 0);
            acc[nt] = __builtin_amdgcn_mfma_f32_16x16x32_bf16(al, bh, acc[nt], 0, 0, 0);
        }
    }

    if (mode == 1) {
#pragma unroll
        for (int nt = 0; nt < 4; ++nt) {
            const int d = j0 + nt * 16 + lr;
            const float bb = b[d];
            float* base = &ke[(((d >> 3) * MK) + i0 + w * 16 + rbase) * 8 + (d & 7)];
#pragma unroll
            for (int j = 0; j < 4; ++j)
                base[j * 8] = __builtin_amdgcn_exp2f((acc[nt][j] + bb) * CSC);
        }
    } else {
        float* dst = (mode == 0) ? qe : vp;
#pragma unroll
        for (int nt = 0; nt < 4; ++nt) {
            const float bb = b[j0 + nt * 16 + lr];
#pragma unroll
            for (int j = 0; j < 4; ++j) {
                float val = acc[nt][j] + bb;
                if (mode == 0) val = __builtin_amdgcn_exp2f(val * CSC);
                dst[(i0 + w * 16 + rbase + j) * DD + j0 + nt * 16 + lr] = val;
            }
        }
    }
}

// ---------------------------------------------------------------------------
// K2: fused scores + softmax. One block per query row; thread t = key m.
// Inner elem: e = qe[d]*ke[d,m]; acc += ww[d]*rcp(e+1)  (3 full + 1 trans,
// zero exp2). (qe,ww) packed pairs -> one ds_read_b128 covers 2 d's.
// kv chunk register-prefetched. (sum(Ww)+bw) shift cancels in softmax.
// ---------------------------------------------------------------------------
__global__ __launch_bounds__(1024) void score_sm(
    const float* __restrict__ qe, const float* __restrict__ kts,
    const float* __restrict__ Ww, const int* __restrict__ mask,
    float* __restrict__ S)
{
    const int n = blockIdx.x;
    const int t = threadIdx.x;            // key index m
    const int lane = t & 63, wave = t >> 6;

    __shared__ float qw[DD * 2];          // packed (qe, Ww) pairs
    __shared__ float red[16];

    if (t < DD) { qw[t * 2] = qe[n * DD + t]; qw[t * 2 + 1] = Ww[t]; }
    __syncthreads();

    const float* kp = kts + t * 8;
    float acc = 0.f;
    float4 k0 = *(const float4*)(kp);
    float4 k1 = *(const float4*)(kp + 4);
    for (int c = 0; c < 64; ++c) {
        float4 p0 = k0, p1 = k1;
        if (c + 1 < 64) {
            p0 = *(const float4*)(kp + (c + 1) * (MK * 8));
            p1 = *(const float4*)(kp + (c + 1) * (MK * 8) + 4);
        }
        float kv[8] = {k0.x, k0.y, k0.z, k0.w, k1.x, k1.y, k1.z, k1.w};
#pragma unroll
        for (int j = 0; j < 8; j += 2) {
            float4 qq = *(const float4*)&qw[(c * 8 + j) * 2]; // qe_j,ww_j,qe_j+1,ww_j+1
            float e0 = qq.x * kv[j];
            float e1 = qq.z * kv[j + 1];
            acc = fmaf(qq.y, __builtin_amdgcn_rcpf(e0 + 1.0f), acc);
            acc = fmaf(qq.w, __builtin_amdgcn_rcpf(e1 + 1.0f), acc);
        }
        k0 = p0; k1 = p1;
    }

    float s = -2.0f * acc;
    s = (mask[n * MK + t] == 1) ? s : -1e6f;

    // block max
    float mx = s;
    for (int o = 32; o > 0; o >>= 1) mx = fmaxf(mx, __shfl_xor(mx, o, 64));
    if (lane == 0) red[wave] = mx;
    __syncthreads();
    if (wave == 0) {
        float r = red[lane & 15];
        for (int o = 8; o > 0; o >>= 1) r = fmaxf(r, __shfl_xor(r, o, 64));
        if (lane == 0) red[0] = r;
    }
    __syncthreads();
    mx = red[0];
    __syncthreads();

    // block sum of exp
    float e = __builtin_amdgcn_exp2f((s - mx) * L2E);
    float sum = e;
    for (int o = 32; o > 0; o >>= 1) sum += __shfl_xor(sum, o, 64);
    if (lane == 0) red[wave] = sum;
    __syncthreads();
    if (wave == 0) {
        float r = red[lane & 15];
        for (int o = 8; o > 0; o >>= 1) r += __shfl_xor(r, o, 64);
        if (lane == 0) red[0] = r;
    }
    __syncthreads();
    sum = red[0];

    S[n * MK + t] = e * __builtin_amdgcn_rcpf(sum);
}

// ---------------------------------------------------------------------------
// K3: context via d-split (no atomics, no output memset).
// Grid (64 n-groups x 4 d-quarters), 512 thr. Block: 4 rows x full m x 128 d.
// Thread t: d = d0+(t&127), m-segment = t>>7 (4 segs x 256 m); segment
// partials combined in LDS, plain store.
// ---------------------------------------------------------------------------
#define XNG 4

__global__ __launch_bounds__(512) void context_v3(const float* __restrict__ S,
                                                  const float* __restrict__ vp,
                                                  float* __restrict__ out)
{
    __shared__ float ws[MK][XNG];          // [m][row] 16 KB
    __shared__ float pacc[4][XNG][128];    // [seg][row][d] 8 KB
    const int t = threadIdx.x;
    const int n0 = blockIdx.x * XNG;
    const int d0 = blockIdx.y * 128;

#pragma unroll
    for (int p = 0; p < 8; ++p) {
        int e = t + p * 512;               // 0..4095
        int nn = e >> 10, m = e & 1023;
        ws[m][nn] = S[(n0 + nn) * MK + m];
    }
    __syncthreads();

    const int d = d0 + (t & 127);
    const int seg = t >> 7;
    float acc[XNG] = {};
    for (int m = seg * 256; m < seg * 256 + 256; ++m) {
        float vv = vp[m * DD + d];
        float4 w = *(const float4*)&ws[m][0];
        acc[0] = fmaf(w.x, vv, acc[0]);
        acc[1] = fmaf(w.y, vv, acc[1]);
        acc[2] = fmaf(w.z, vv, acc[2]);
        acc[3] = fmaf(w.w, vv, acc[3]);
    }
#pragma unroll
    for (int nn = 0; nn < XNG; ++nn) pacc[seg][nn][t & 127] = acc[nn];
    __syncthreads();

    if (t < XNG * 128) {
        int nn = t >> 7, dd = t & 127;
        float r = pacc[0][nn][dd] + pacc[1][nn][dd]
                + pacc[2][nn][dd] + pacc[3][nn][dd];
        out[(n0 + nn) * DD + d0 + dd] = r;
    }
}

// ---------------------------------------------------------------------------
extern "C" void kernel_launch(void* const* d_in, const int* in_sizes, int n_in,
                              void* d_out, int out_size, void* d_ws, size_t ws_size,
                              hipStream_t stream)
{
    const float* q    = (const float*)d_in[0];
    const float* k    = (const float*)d_in[1];
    const float* v    = (const float*)d_in[2];
    const int*   mask = (const int*)  d_in[3];
    const float* WQ   = (const float*)d_in[4];
    const float* bQ   = (const float*)d_in[5];
    const float* WK   = (const float*)d_in[6];
    const float* bK   = (const float*)d_in[7];
    const float* WV   = (const float*)d_in[8];
    const float* bV   = (const float*)d_in[9];
    const float* Ww   = (const float*)d_in[10];
    const float* bw   = (const float*)d_in[11];
    (void)bw;  // cancels in softmax (shift invariance)
    float* out = (float*)d_out;

    // f32 workspace
    float* qe  = (float*)d_ws;           // 131072 (exp2-domain q-projection)
    float* ke  = qe + NQ * DD;           // 524288 (exp2-domain, kt8 tiled)
    float* vp  = ke + DD * MK;           // 524288
    float* S   = vp + MK * DD;           // 262144 (final softmax weights)
    // bf16 hi/lo workspace (swizzled fragment layout)
    unsigned short* p16  = (unsigned short*)(S + NQ * MK);
    unsigned short* qhi  = p16;              p16 += NQ * DD;
    unsigned short* qlo  = p16;              p16 += NQ * DD;
    unsigned short* khi  = p16;              p16 += MK * DD;
    unsigned short* klo  = p16;              p16 += MK * DD;
    unsigned short* vhi  = p16;              p16 += MK * DD;
    unsigned short* vlo  = p16;              p16 += MK * DD;
    unsigned short* wqhi = p16;              p16 += DD * DD;
    unsigned short* wqlo = p16;              p16 += DD * DD;
    unsigned short* wkhi = p16;              p16 += DD * DD;
    unsigned short* wklo = p16;              p16 += DD * DD;
    unsigned short* wvhi = p16;              p16 += DD * DD;
    unsigned short* wvlo = p16;

    convert_split<<<1920, 256, 0, stream>>>(q, k, v, WQ, WK, WV,
        qhi, qlo, khi, klo, vhi, vlo, wqhi, wqlo, wkhi, wklo, wvhi, wvlo);

    proj_mfma<<<288, 256, 0, stream>>>(qhi, qlo, khi, klo, vhi, vlo,
        wqhi, wqlo, wkhi, wklo, wvhi, wvlo, bQ, bK, bV, qe, ke, vp);

    score_sm<<<NQ, 1024, 0, stream>>>(qe, ke, Ww, mask, S);

    context_v3<<<dim3(NQ / XNG, 4), 512, 0, stream>>>(S, vp, out);
}

// Round 15
// 144.318 us; speedup vs baseline: 1.2305x; 1.0023x over previous
//
#include <hip/hip_runtime.h>

#define NQ 256
#define MK 1024
#define DD 512
#define CSC 2.8853900817779268f   // 2*log2(e): tanh(x) = 1 - 2/(exp2(CSC*x)+1)
#define L2E 1.4426950408889634f

typedef __attribute__((ext_vector_type(8))) short short8;
typedef __attribute__((ext_vector_type(4))) float floatx4;

// Swizzled MFMA-fragment layout for row-major [rows][512] bf16 arrays:
// element (i,d) -> ((i/16)*16 + d/32)*512 + ((d/8)&3)*128 + (i&15)*8 + (d&7).
// A wave's 16x32 fragment tile = one contiguous 1KB block (lane l at l*8).
__device__ inline int swz(int i, int d)
{
    return (((i >> 4) * 16 + (d >> 5)) << 9) | (((d >> 3) & 3) << 7)
         | ((i & 15) << 3) | (d & 7);
}

// ---------------------------------------------------------------------------
// K0: split f32 -> bf16 hi/lo pairs (swizzled layout). 1920 blocks x 256.
// ---------------------------------------------------------------------------
__device__ inline void bsplit(float x, unsigned short& h, unsigned short& l)
{
    unsigned u = __float_as_uint(x);
    unsigned hr = (u + 0x7FFFu + ((u >> 16) & 1u)) >> 16;   // RN bf16
    h = (unsigned short)hr;
    float hf = __uint_as_float(hr << 16);
    unsigned ul = __float_as_uint(x - hf);
    l = (unsigned short)((ul + 0x7FFFu + ((ul >> 16) & 1u)) >> 16);
}

__global__ __launch_bounds__(256) void convert_split(
    const float* __restrict__ q, const float* __restrict__ k, const float* __restrict__ v,
    const float* __restrict__ WQ, const float* __restrict__ WK, const float* __restrict__ WV,
    unsigned short* __restrict__ qhi, unsigned short* __restrict__ qlo,
    unsigned short* __restrict__ khi, unsigned short* __restrict__ klo,
    unsigned short* __restrict__ vhi, unsigned short* __restrict__ vlo,
    unsigned short* __restrict__ wqhi, unsigned short* __restrict__ wqlo,
    unsigned short* __restrict__ wkhi, unsigned short* __restrict__ wklo,
    unsigned short* __restrict__ wvhi, unsigned short* __restrict__ wvlo)
{
    const int i4 = blockIdx.x * 256 + threadIdx.x;   // float4 index
    const float* src; unsigned short *dh, *dl; int li;
    if (i4 < 32768)       { src = q;  dh = qhi;  dl = qlo;  li = i4; }
    else if (i4 < 163840) { src = k;  dh = khi;  dl = klo;  li = i4 - 32768; }
    else if (i4 < 294912) { src = v;  dh = vhi;  dl = vlo;  li = i4 - 163840; }
    else if (i4 < 360448) { src = WQ; dh = wqhi; dl = wqlo; li = i4 - 294912; }
    else if (i4 < 425984) { src = WK; dh = wkhi; dl = wklo; li = i4 - 360448; }
    else                  { src = WV; dh = wvhi; dl = wvlo; li = i4 - 425984; }

    float4 x = *(const float4*)&src[li * 4];
    ushort4 h, l;
    bsplit(x.x, h.x, l.x); bsplit(x.y, h.y, l.y);
    bsplit(x.z, h.z, l.z); bsplit(x.w, h.w, l.w);

    const int e = li * 4;                 // element index; d%4==0
    const int o = swz(e >> 9, e & 511);   // 8B-aligned (d&7 in {0,4})
    *(ushort4*)&dh[o] = h;
    *(ushort4*)&dl[o] = l;
}

// ---------------------------------------------------------------------------
// K1: projections via split-bf16 MFMA, swizzled-coalesced fragment loads.
// 288 blocks, 4 waves, 64x64 tile (wave = 16-row strip, 4 n-tiles).
//   mode 0: qe  = exp2(CSC*(q@WQ.T+bQ))          [256x512] row-major
//   mode 1: ke  = exp2(CSC*(k@WK.T+bK)) TILED    ke[((d>>3)*MK+m)*8+(d&7)]
//   mode 2: vp  = v@WV.T+bV                      [1024x512] row-major
// (score uses exp2(a+b) = exp2(a)*exp2(b); args bounded ~|15| -> no overflow)
// ---------------------------------------------------------------------------
__global__ __launch_bounds__(256) void proj_mfma(
    const unsigned short* __restrict__ qhi, const unsigned short* __restrict__ qlo,
    const unsigned short* __restrict__ khi, const unsigned short* __restrict__ klo,
    const unsigned short* __restrict__ vhi, const unsigned short* __restrict__ vlo,
    const unsigned short* __restrict__ wqhi, const unsigned short* __restrict__ wqlo,
    const unsigned short* __restrict__ wkhi, const unsigned short* __restrict__ wklo,
    const unsigned short* __restrict__ wvhi, const unsigned short* __restrict__ wvlo,
    const float* __restrict__ bQ, const float* __restrict__ bK, const float* __restrict__ bV,
    float* __restrict__ qe, float* __restrict__ ke, float* __restrict__ vp)
{
    int t = blockIdx.x;
    const unsigned short *Xh, *Xl, *Wh, *Wl; const float* b; int mode;
    if (t < 32)       { mode = 0; Xh = qhi; Xl = qlo; Wh = wqhi; Wl = wqlo; b = bQ; }
    else if (t < 160) { mode = 1; t -= 32;  Xh = khi; Xl = klo; Wh = wkhi; Wl = wklo; b = bK; }
    else              { mode = 2; t -= 160; Xh = vhi; Xl = vlo; Wh = wvhi; Wl = wvlo; b = bV; }
    const int i0 = (t >> 3) * 64;
    const int j0 = (t & 7) * 64;

    const int l  = threadIdx.x & 63;
    const int w  = threadIdx.x >> 6;
    const int lr = l & 15;             // A-row / B-col / D-col within tile
    const int rbase = (l >> 4) * 4;    // D-row base

    const unsigned short* Ah = Xh + ((i0 >> 4) + w) * 8192 + l * 8;
    const unsigned short* Al = Xl + ((i0 >> 4) + w) * 8192 + l * 8;
    const unsigned short* Bh = Wh + (j0 >> 4) * 8192 + l * 8;
    const unsigned short* Bl = Wl + (j0 >> 4) * 8192 + l * 8;

    floatx4 acc[4] = {{0,0,0,0},{0,0,0,0},{0,0,0,0},{0,0,0,0}};

#pragma unroll
    for (int kc = 0; kc < 16; ++kc) {
        short8 ah = *(const short8*)(Ah + kc * 512);
        short8 al = *(const short8*)(Al + kc * 512);
#pragma unroll
        for (int nt = 0; nt < 4; ++nt) {
            short8 bh = *(const short8*)(Bh + nt * 8192 + kc * 512);
            short8 bl = *(const short8*)(Bl + nt * 8192 + kc * 512);
            acc[nt] = __builtin_amdgcn_mfma_f32_16x16x32_bf16(ah, bh, acc[nt], 0, 0, 0);
            acc[nt] = __builtin_amdgcn_mfma_f32_16x16x32_bf16(ah, bl, acc[nt], 0, 0, 0);
            acc[nt] = __builtin_amdgcn_mfma_f32_16x16x32_bf16(al, bh, acc[nt], 0, 0, 0);
        }
    }

    if (mode == 1) {
#pragma unroll
        for (int nt = 0; nt < 4; ++nt) {
            const int d = j0 + nt * 16 + lr;
            const float bb = b[d];
            float* base = &ke[(((d >> 3) * MK) + i0 + w * 16 + rbase) * 8 + (d & 7)];
#pragma unroll
            for (int j = 0; j < 4; ++j)
                base[j * 8] = __builtin_amdgcn_exp2f((acc[nt][j] + bb) * CSC);
        }
    } else {
        float* dst = (mode == 0) ? qe : vp;
#pragma unroll
        for (int nt = 0; nt < 4; ++nt) {
            const float bb = b[j0 + nt * 16 + lr];
#pragma unroll
            for (int j = 0; j < 4; ++j) {
                float val = acc[nt][j] + bb;
                if (mode == 0) val = __builtin_amdgcn_exp2f(val * CSC);
                dst[(i0 + w * 16 + rbase + j) * DD + j0 + nt * 16 + lr] = val;
            }
        }
    }
}

// ---------------------------------------------------------------------------
// K2: scores (pre-softmax). Grid (4 m-quarters, 64 n-quads) = 256 blocks,
// 512 thr = 8 waves = 4 m-groups x 2 d-halves. 4 queries share every kv load
// (ke L2 traffic /4); qe/Ww are wave-uniform scalar loads (readfirstlane'd
// d-half). Inner elem: e = fma(qe,kv,1); acc += ww*rcp(e)  (2 fma + 1 trans).
// d-halves combined via LDS; masked write of raw scores to S.
// ---------------------------------------------------------------------------
#define SN 4

__global__ __launch_bounds__(512) void score_v4(
    const float* __restrict__ qe, const float* __restrict__ ke,
    const float* __restrict__ Ww, const int* __restrict__ mask,
    float* __restrict__ S)
{
    const int t = threadIdx.x;
    const int lane = t & 63;
    const int w = t >> 6;                                    // 8 waves
    const int mg = w & 3;                                    // m-group
    const int dh = __builtin_amdgcn_readfirstlane(w >> 2);   // d-half (SGPR)
    const int m0 = blockIdx.x * 256;
    const int m  = m0 + mg * 64 + lane;
    const int n0 = blockIdx.y * SN;

    __shared__ float part[2][SN][256];

    const float* qb = qe + n0 * DD + dh * 256;   // wave-uniform base
    const float* wb = Ww + dh * 256;             // wave-uniform base
    const float* kb = ke + (size_t)(dh * 32) * (MK * 8) + m * 8;

    float acc[SN] = {0.f, 0.f, 0.f, 0.f};
    float4 k0 = *(const float4*)(kb);
    float4 k1 = *(const float4*)(kb + 4);
    for (int c = 0; c < 32; ++c) {
        float4 p0 = k0, p1 = k1;
        if (c + 1 < 32) {
            p0 = *(const float4*)(kb + (c + 1) * (MK * 8));
            p1 = *(const float4*)(kb + (c + 1) * (MK * 8) + 4);
        }
        float kv[8] = {k0.x, k0.y, k0.z, k0.w, k1.x, k1.y, k1.z, k1.w};
#pragma unroll
        for (int j = 0; j < 8; ++j) {
            const float ww = wb[c * 8 + j];                  // uniform -> s_load
#pragma unroll
            for (int n = 0; n < SN; ++n) {
                float e = fmaf(qb[n * DD + c * 8 + j], kv[j], 1.0f);
                acc[n] = fmaf(ww, __builtin_amdgcn_rcpf(e), acc[n]);
            }
        }
        k0 = p0; k1 = p1;
    }

#pragma unroll
    for (int n = 0; n < SN; ++n) part[dh][n][mg * 64 + lane] = acc[n];
    __syncthreads();

    if (w < 4) {   // mg == w, dh == 0 slice writers
#pragma unroll
        for (int n = 0; n < SN; ++n) {
            float s = -2.0f * (part[0][n][mg * 64 + lane] + part[1][n][mg * 64 + lane]);
            s = (mask[(n0 + n) * MK + m] == 1) ? s : -1e6f;
            S[(n0 + n) * MK + m] = s;
        }
    }
}

// ---------------------------------------------------------------------------
// K3: row softmax over m (1024) — one block per query row.
// ---------------------------------------------------------------------------
__global__ __launch_bounds__(256) void softmax_kernel(float* __restrict__ S)
{
    const int n = blockIdx.x;
    const int t = threadIdx.x;
    const int lane = t & 63, wave = t >> 6;
    __shared__ float red[4];

    float v[4];
    float mx = -3.4e38f;
#pragma unroll
    for (int i = 0; i < 4; ++i) {
        v[i] = S[n * MK + t + i * 256];
        mx = fmaxf(mx, v[i]);
    }
    for (int o = 32; o > 0; o >>= 1) mx = fmaxf(mx, __shfl_xor(mx, o, 64));
    if (lane == 0) red[wave] = mx;
    __syncthreads();
    mx = fmaxf(fmaxf(red[0], red[1]), fmaxf(red[2], red[3]));
    __syncthreads();

    float sum = 0.f;
#pragma unroll
    for (int i = 0; i < 4; ++i) {
        v[i] = __builtin_amdgcn_exp2f((v[i] - mx) * L2E);
        sum += v[i];
    }
    for (int o = 32; o > 0; o >>= 1) sum += __shfl_xor(sum, o, 64);
    if (lane == 0) red[wave] = sum;
    __syncthreads();
    sum = red[0] + red[1] + red[2] + red[3];

    const float inv = __builtin_amdgcn_rcpf(sum);
#pragma unroll
    for (int i = 0; i < 4; ++i) S[n * MK + t + i * 256] = v[i] * inv;
}

// ---------------------------------------------------------------------------
// K4: context via d-split (no atomics, no output memset).
// Grid (64 n-groups x 4 d-quarters), 512 thr. Block: 4 rows x full m x 128 d.
// ---------------------------------------------------------------------------
#define XNG 4

__global__ __launch_bounds__(512) void context_v3(const float* __restrict__ S,
                                                  const float* __restrict__ vp,
                                                  float* __restrict__ out)
{
    __shared__ float ws[MK][XNG];          // [m][row] 16 KB
    __shared__ float pacc[4][XNG][128];    // [seg][row][d] 8 KB
    const int t = threadIdx.x;
    const int n0 = blockIdx.x * XNG;
    const int d0 = blockIdx.y * 128;

#pragma unroll
    for (int p = 0; p < 8; ++p) {
        int e = t + p * 512;               // 0..4095
        int nn = e >> 10, m = e & 1023;
        ws[m][nn] = S[(n0 + nn) * MK + m];
    }
    __syncthreads();

    const int d = d0 + (t & 127);
    const int seg = t >> 7;
    float acc[XNG] = {};
    for (int m = seg * 256; m < seg * 256 + 256; ++m) {
        float vv = vp[m * DD + d];
        float4 w = *(const float4*)&ws[m][0];
        acc[0] = fmaf(w.x, vv, acc[0]);
        acc[1] = fmaf(w.y, vv, acc[1]);
        acc[2] = fmaf(w.z, vv, acc[2]);
        acc[3] = fmaf(w.w, vv, acc[3]);
    }
#pragma unroll
    for (int nn = 0; nn < XNG; ++nn) pacc[seg][nn][t & 127] = acc[nn];
    __syncthreads();

    if (t < XNG * 128) {
        int nn = t >> 7, dd = t & 127;
        float r = pacc[0][nn][dd] + pacc[1][nn][dd]
                + pacc[2][nn][dd] + pacc[3][nn][dd];
        out[(n0 + nn) * DD + d0 + dd] = r;
    }
}

// ---------------------------------------------------------------------------
extern "C" void kernel_launch(void* const* d_in, const int* in_sizes, int n_in,
                              void* d_out, int out_size, void* d_ws, size_t ws_size,
                              hipStream_t stream)
{
    const float* q    = (const float*)d_in[0];
    const float* k    = (const float*)d_in[1];
    const float* v    = (const float*)d_in[2];
    const int*   mask = (const int*)  d_in[3];
    const float* WQ   = (const float*)d_in[4];
    const float* bQ   = (const float*)d_in[5];
    const float* WK   = (const float*)d_in[6];
    const float* bK   = (const float*)d_in[7];
    const float* WV   = (const float*)d_in[8];
    const float* bV   = (const float*)d_in[9];
    const float* Ww   = (const float*)d_in[10];
    const float* bw   = (const float*)d_in[11];
    (void)bw;  // cancels in softmax (shift invariance)
    float* out = (float*)d_out;

    // f32 workspace
    float* qe  = (float*)d_ws;           // 131072 (exp2-domain q-projection)
    float* ke  = qe + NQ * DD;           // 524288 (exp2-domain, kt8 tiled)
    float* vp  = ke + DD * MK;           // 524288
    float* S   = vp + MK * DD;           // 262144
    // bf16 hi/lo workspace (swizzled fragment layout)
    unsigned short* p16  = (unsigned short*)(S + NQ * MK);
    unsigned short* qhi  = p16;              p16 += NQ * DD;
    unsigned short* qlo  = p16;              p16 += NQ * DD;
    unsigned short* khi  = p16;              p16 += MK * DD;
    unsigned short* klo  = p16;              p16 += MK * DD;
    unsigned short* vhi  = p16;              p16 += MK * DD;
    unsigned short* vlo  = p16;              p16 += MK * DD;
    unsigned short* wqhi = p16;              p16 += DD * DD;
    unsigned short* wqlo = p16;              p16 += DD * DD;
    unsigned short* wkhi = p16;              p16 += DD * DD;
    unsigned short* wklo = p16;              p16 += DD * DD;
    unsigned short* wvhi = p16;              p16 += DD * DD;
    unsigned short* wvlo = p16;

    convert_split<<<1920, 256, 0, stream>>>(q, k, v, WQ, WK, WV,
        qhi, qlo, khi, klo, vhi, vlo, wqhi, wqlo, wkhi, wklo, wvhi, wvlo);

    proj_mfma<<<288, 256, 0, stream>>>(qhi, qlo, khi, klo, vhi, vlo,
        wqhi, wqlo, wkhi, wklo, wvhi, wvlo, bQ, bK, bV, qe, ke, vp);

    score_v4<<<dim3(4, NQ / SN), 512, 0, stream>>>(qe, ke, Ww, mask, S);

    softmax_kernel<<<NQ, 256, 0, stream>>>(S);

    context_v3<<<dim3(NQ / XNG, 4), 512, 0, stream>>>(S, vp, out);
}